// Round 10
// baseline (36.699 us; speedup 1.0000x reference)
//
#include <hip/hip_runtime.h>
#include <hip/hip_bf16.h>

// Problem dims (fixed by setup_inputs)
#define BS     256
#define N_BAG  128
#define DXD    32
#define DYD    10
#define M_COMP 2048
#define NTILES 8              // n-tiles (128/16)
#define WAVES  16             // block = 1024 threads
#define MT_PW  16             // m-tiles per wave-pair member (128 tiles / 8 pairs)

typedef __attribute__((ext_vector_type(8))) short short8v;   // 8 bf16 (4 VGPRs)
typedef __attribute__((ext_vector_type(4))) float f32x4;

static __device__ __forceinline__ unsigned int pkbf(float a, float b) {
    // RNE pack of two f32 -> 2x bf16 in one u32 (v_cvt_pk_bf16_f32)
    unsigned short ha = __bfloat16_as_ushort(__float2bfloat16(a));
    unsigned short hb = __bfloat16_as_ushort(__float2bfloat16(b));
    return (unsigned int)ha | ((unsigned int)hb << 16);
}
static __device__ __forceinline__ float fast_exp2(float x) {
#if __has_builtin(__builtin_amdgcn_exp2f)
    return __builtin_amdgcn_exp2f(x);     // trans pipe (staging only)
#else
    return __expf(x * 0.6931471805599453f);
#endif
}

// VALU-only 2^x accumulate: c += 2^x. Valid for x > -120 (here x in [-9, 0.3]).
// Rel err < 1e-6 (Cephes exp2f poly). ~13 VALU ops, no v_exp_f32.
static __device__ __forceinline__ float exp2_acc(float x, float c) {
    float n  = __builtin_rintf(x);             // v_rndne_f32
    float f  = x - n;                          // [-0.5, 0.5]
    int   ni = (int)n;
    float p  = 1.535336188319500e-4f;
    p = fmaf(p, f, 1.339887440266574e-3f);
    p = fmaf(p, f, 9.618437357674640e-3f);
    p = fmaf(p, f, 5.550332471162809e-2f);
    p = fmaf(p, f, 2.402264791363012e-1f);
    p = fmaf(p, f, 6.931472028550421e-1f);
    p = fmaf(p, f, 1.0f);
    float s  = __int_as_float((ni + 127) << 23);   // 2^n
    return fmaf(s, p, c);                      // c += 2^n * 2^f
}

// One block per batch row b; 16 waves; 1 block/CU. K^2 = 2^(c2*a2[n] - 2c2*dot) * 2^(c2*b2[m]).
// n-SPLIT: wave-pair wp (0..7) owns 16 m-tiles; member 'half' owns 4 of 8 n-tiles.
// Halves the resident fragment set (32 VGPR freed) so the VALU-poly exp runs spill-free.
__global__ __launch_bounds__(1024, 4) void fused_kernel(
    const float* __restrict__ X,        // (BS, N_BAG, DXD)
    const float* __restrict__ sig_p,    // scalar
    const float* __restrict__ c_x,      // (M_COMP, DXD)
    const float* __restrict__ c_y,      // (M_COMP, DYD)
    const float* __restrict__ comp_w,   // (M_COMP,)
    float* __restrict__ out)            // (BS, DYD)
{
    __shared__ short8v Af[NTILES][64];     // A' fragments (8 KB)
    __shared__ float   a2part[N_BAG][4];
    __shared__ float   a2c[N_BAG];         // c2 * ||x_n||^2
    __shared__ float   ebw[M_COMP];        // 2^(c2*b2[m]) * comp_w[m] / N  (8 KB)
    __shared__ float   ow_s[2][M_COMP];    // per-n-half partial sums (16 KB)
    __shared__ float   red[WAVES][12];
    __shared__ float   sm[12];

    const int tid = threadIdx.x;
    const int b   = blockIdx.x;

    const float sgm = fmaxf(sig_p[0], 1e-3f);
    const float c2  = -1.4426950408889634f / (sgm * sgm);  // -log2(e)/sigma^2 (<0)
    const float sA  = -2.0f * c2;                          // A-side scale (>0)

    // ---- stage A' = sA*X as bf16 fragments + row norms (threads 0..511) ----
    if (tid < 512) {
        const int n = tid >> 2, g4 = tid & 3;
        const float4* Xr = (const float4*)(X + ((size_t)(b * N_BAG + n) * DXD + 8 * g4));
        float4 v0 = Xr[0], v1 = Xr[1];
        float s = 0.f;
        s = fmaf(v0.x, v0.x, s); s = fmaf(v0.y, v0.y, s);
        s = fmaf(v0.z, v0.z, s); s = fmaf(v0.w, v0.w, s);
        s = fmaf(v1.x, v1.x, s); s = fmaf(v1.y, v1.y, s);
        s = fmaf(v1.z, v1.z, s); s = fmaf(v1.w, v1.w, s);
        union { unsigned int u4[4]; short8v s8; } cv;
        cv.u4[0] = pkbf(sA * v0.x, sA * v0.y); cv.u4[1] = pkbf(sA * v0.z, sA * v0.w);
        cv.u4[2] = pkbf(sA * v1.x, sA * v1.y); cv.u4[3] = pkbf(sA * v1.z, sA * v1.w);
        Af[n >> 4][g4 * 16 + (n & 15)] = cv.s8;
        a2part[n][g4] = s;
    }
    // ---- stage ebw[m] = 2^(c2*||c_x[m]||^2) * comp_w[m]/N for all 2048 m ----
#pragma unroll
    for (int k = 0; k < 2; ++k) {
        const int m = tid + 1024 * k;
        const float4* cp = (const float4*)(c_x + (size_t)m * DXD);
        float s = 0.f;
#pragma unroll
        for (int j = 0; j < 8; ++j) {
            float4 v = cp[j];
            s = fmaf(v.x, v.x, s); s = fmaf(v.y, v.y, s);
            s = fmaf(v.z, v.z, s); s = fmaf(v.w, v.w, s);
        }
        ebw[m] = fast_exp2(c2 * s) * comp_w[m] * (1.0f / N_BAG);
    }
    __syncthreads();
    if (tid < N_BAG)
        a2c[tid] = c2 * (a2part[tid][0] + a2part[tid][1] +
                         a2part[tid][2] + a2part[tid][3]);
    __syncthreads();

    // ---- per-wave register state: 4 A-frags + 4 seed rows (one n-half, 32 VGPR) ----
    const int lane = tid & 63, wv = tid >> 6;
    const int half = wv & 1, wp = wv >> 1;          // n-half 0/1, wave-pair 0..7
    const int r = lane & 15, gq = lane >> 4, rowg = gq * 4;
    short8v Ah[4];
    f32x4   a2f[4];
#pragma unroll
    for (int t = 0; t < 4; ++t) {
        Ah[t]  = Af[half * 4 + t][lane];
        a2f[t] = *(const f32x4*)&a2c[(half * 4 + t) * 16 + rowg];
    }

    const int    mt_base = wp * MT_PW;              // tiles [mt_base, mt_base+16)
    const float* cxp     = c_x + (size_t)(mt_base * 16 + r) * DXD + 8 * gq;

    float4 p0 = *(const float4*)(cxp);
    float4 p1 = *(const float4*)(cxp + 4);

#pragma unroll
    for (int i = 0; i < MT_PW; ++i) {
        // prefetch next c_x tile (static predicate under full unroll)
        float4 q0, q1;
        if (i + 1 < MT_PW) {
            q0 = *(const float4*)(cxp + (i + 1) * 16 * DXD);
            q1 = *(const float4*)(cxp + (i + 1) * 16 * DXD + 4);
        }
        union { unsigned int u4[4]; short8v s8; } bc;
        bc.u4[0] = pkbf(p0.x, p0.y); bc.u4[1] = pkbf(p0.z, p0.w);
        bc.u4[2] = pkbf(p1.x, p1.y); bc.u4[3] = pkbf(p1.z, p1.w);

        float cs0 = 0.f, cs1 = 0.f, cs2 = 0.f, cs3 = 0.f;
#pragma unroll
        for (int t = 0; t < 4; ++t) {
            f32x4 acc = __builtin_amdgcn_mfma_f32_16x16x32_bf16(Ah[t], bc.s8, a2f[t], 0, 0, 0);
            cs0 = exp2_acc(acc[0], cs0);
            cs1 = exp2_acc(acc[1], cs1);
            cs2 = exp2_acc(acc[2], cs2);
            cs3 = exp2_acc(acc[3], cs3);
        }
        float csum = (cs0 + cs1) + (cs2 + cs3);
        csum += __shfl_xor(csum, 16, 64);
        csum += __shfl_xor(csum, 32, 64);           // sum over this wave's 64 n-rows
        if (lane < 16) ow_s[half][(mt_base + i) * 16 + r] = csum;
        p0 = q0; p1 = q1;
    }
    __syncthreads();

    // ---- phase 2: coalesced projection over all 2048 m's; block-reduce; write out ----
    float vals[DYD + 1];
#pragma unroll
    for (int v = 0; v <= DYD; ++v) vals[v] = 0.f;
#pragma unroll
    for (int k = 0; k < 2; ++k) {
        const int m = tid + 1024 * k;
        const float w = (ow_s[0][m] + ow_s[1][m]) * ebw[m];
        const float2* cyp = (const float2*)(c_y + (size_t)m * DYD);
        float2 y0 = cyp[0], y1 = cyp[1], y2 = cyp[2], y3 = cyp[3], y4 = cyp[4];
        float cy[DYD] = {y0.x, y0.y, y1.x, y1.y, y2.x, y2.y, y3.x, y3.y, y4.x, y4.y};
        float ny = 0.f;
#pragma unroll
        for (int d = 0; d < DYD; ++d) ny = fmaf(cy[d], cy[d], ny);
        const float yw = w * __builtin_amdgcn_rcpf(ny);
        vals[0] += w;
#pragma unroll
        for (int d = 0; d < DYD; ++d) vals[1 + d] = fmaf(yw, cy[d] * cy[d], vals[1 + d]);
    }
#pragma unroll
    for (int v = 0; v <= DYD; ++v) {
        float x = vals[v];
#pragma unroll
        for (int off = 32; off > 0; off >>= 1) x += __shfl_down(x, off, 64);
        if (lane == 0) red[wv][v] = x;
    }
    __syncthreads();
    if (tid <= DYD) {
        float s = 0.f;
#pragma unroll
        for (int w16 = 0; w16 < WAVES; ++w16) s += red[w16][tid];
        sm[tid] = s;
    }
    __syncthreads();
    if (tid < DYD) {
        float d = sm[0];
        d = (d == 0.f) ? 1e-16f : d;
        out[(size_t)b * DYD + tid] = sm[1 + tid] / d;
    }
}

extern "C" void kernel_launch(void* const* d_in, const int* in_sizes, int n_in,
                              void* d_out, int out_size, void* d_ws, size_t ws_size,
                              hipStream_t stream) {
    const float* X      = (const float*)d_in[0];  // (256,128,32)
    const float* sigma  = (const float*)d_in[1];  // scalar
    const float* c_x    = (const float*)d_in[2];  // (2048,32)
    const float* c_y    = (const float*)d_in[3];  // (2048,10)
    const float* comp_w = (const float*)d_in[4];  // (2048,)
    float*       out    = (float*)d_out;          // (256,10)

    fused_kernel<<<BS, 1024, 0, stream>>>(X, sigma, c_x, c_y, comp_w, out);
}

// Round 11
// 33.977 us; speedup vs baseline: 1.0801x; 1.0801x over previous
//
#include <hip/hip_runtime.h>
#include <hip/hip_bf16.h>

// Problem dims (fixed by setup_inputs)
#define BS     256
#define N_BAG  128
#define DXD    32
#define DYD    10
#define M_COMP 2048
#define NTILES 8              // n-tiles (128/16)
#define WAVES  16             // block = 1024 threads
#define MT_PW  8              // m-tiles per wave (128 tiles / 16 waves)

typedef __attribute__((ext_vector_type(8))) short short8v;   // 8 bf16 (4 VGPRs)
typedef __attribute__((ext_vector_type(4))) float f32x4;

static __device__ __forceinline__ unsigned int pkbf(float a, float b) {
    // RNE pack of two f32 -> 2x bf16 in one u32 (v_cvt_pk_bf16_f32)
    unsigned short ha = __bfloat16_as_ushort(__float2bfloat16(a));
    unsigned short hb = __bfloat16_as_ushort(__float2bfloat16(b));
    return (unsigned int)ha | ((unsigned int)hb << 16);
}
static __device__ __forceinline__ float fast_exp2(float x) {
#if __has_builtin(__builtin_amdgcn_exp2f)
    return __builtin_amdgcn_exp2f(x);     // trans pipe
#else
    return __expf(x * 0.6931471805599453f);
#endif
}

// LUT exp2-accumulate: c += 2^(t/64), t = 64*log2-exponent (pre-scaled upstream).
// T[j] = 2^(j/64) in LDS (64 entries); residual r in [0,1) corrected by a 2-term
// poly (rel err ~2e-7); integer octave applied via v_ldexp_f32 (graceful underflow).
// ~11 VALU + 1 ds_read; ~5 live temps (vs ~24 for the full Cephes poly).
static __device__ __forceinline__ float exp2lut_acc(float t, const float* lut, float c) {
    float f = __builtin_floorf(t);            // v_floor_f32
    float r = t - f;                          // [0, 1)
    int   i = (int)f;                         // v_cvt_i32_f32 (exact here)
    float T = lut[i & 63];                    // ds_read_b32, 2^((i&63)/64)
    float corr = fmaf(r, fmaf(r, 5.8645e-5f, 1.0830424697e-2f), 1.0f);  // ~2^(r/64)
    float v = ldexpf(T, i >> 6);              // v_ldexp_f32: * 2^octave
    return fmaf(v, corr, c);
}

// One block per batch row b; 16 waves; 1 block/CU (4 waves/SIMD, <=128 VGPR).
// K^2 = 2^(c2*a2[n] - 2c2*dot) * 2^(c2*b2[m]); MFMA emits t = 64*c2*(a2-2dot) directly
// (the x64 LUT scale folded into sA and the seed). Epilogue: 1 element via v_exp_f32
// (trans pipe), 3 via LDS-LUT (VALU+DS pipes). ebw/b2 factor applied in phase 2.
__global__ __launch_bounds__(1024, 4) void fused_kernel(
    const float* __restrict__ X,        // (BS, N_BAG, DXD)
    const float* __restrict__ sig_p,    // scalar
    const float* __restrict__ c_x,      // (M_COMP, DXD)
    const float* __restrict__ c_y,      // (M_COMP, DYD)
    const float* __restrict__ comp_w,   // (M_COMP,)
    float* __restrict__ out)            // (BS, DYD)
{
    __shared__ short8v Af[NTILES][64];     // A' fragments (8 KB)
    __shared__ float   a2part[N_BAG][4];
    __shared__ float   a2c[N_BAG];         // 64 * c2 * ||x_n||^2
    __shared__ float   ebw[M_COMP];        // 2^(c2*b2[m]) * comp_w[m] / N  (8 KB)
    __shared__ float   ow_s[M_COMP];       // sum_n 2^t per m (8 KB)
    __shared__ float   lut[64];            // 2^(j/64)
    __shared__ float   red[WAVES][12];
    __shared__ float   sm[12];

    const int tid = threadIdx.x;
    const int b   = blockIdx.x;

    const float sgm = fmaxf(sig_p[0], 1e-3f);
    const float c2  = -1.4426950408889634f / (sgm * sgm);  // -log2(e)/sigma^2 (<0)
    const float c2t = 64.0f * c2;                          // LUT scale folded in
    const float sA  = -2.0f * c2t;                         // A-side scale (>0)

    // ---- stage A' = sA*X as bf16 fragments + row norms (threads 0..511) ----
    if (tid < 512) {
        const int n = tid >> 2, g4 = tid & 3;
        const float4* Xr = (const float4*)(X + ((size_t)(b * N_BAG + n) * DXD + 8 * g4));
        float4 v0 = Xr[0], v1 = Xr[1];
        float s = 0.f;
        s = fmaf(v0.x, v0.x, s); s = fmaf(v0.y, v0.y, s);
        s = fmaf(v0.z, v0.z, s); s = fmaf(v0.w, v0.w, s);
        s = fmaf(v1.x, v1.x, s); s = fmaf(v1.y, v1.y, s);
        s = fmaf(v1.z, v1.z, s); s = fmaf(v1.w, v1.w, s);
        union { unsigned int u4[4]; short8v s8; } cv;
        cv.u4[0] = pkbf(sA * v0.x, sA * v0.y); cv.u4[1] = pkbf(sA * v0.z, sA * v0.w);
        cv.u4[2] = pkbf(sA * v1.x, sA * v1.y); cv.u4[3] = pkbf(sA * v1.z, sA * v1.w);
        Af[n >> 4][g4 * 16 + (n & 15)] = cv.s8;
        a2part[n][g4] = s;
    }
    // ---- LUT init: 2^(j/64), j = 0..63 ----
    if (tid < 64) lut[tid] = fast_exp2((float)tid * 0.015625f);
    // ---- stage ebw[m] = 2^(c2*||c_x[m]||^2) * comp_w[m]/N for all 2048 m ----
#pragma unroll
    for (int k = 0; k < 2; ++k) {
        const int m = tid + 1024 * k;
        const float4* cp = (const float4*)(c_x + (size_t)m * DXD);
        float s = 0.f;
#pragma unroll
        for (int j = 0; j < 8; ++j) {
            float4 v = cp[j];
            s = fmaf(v.x, v.x, s); s = fmaf(v.y, v.y, s);
            s = fmaf(v.z, v.z, s); s = fmaf(v.w, v.w, s);
        }
        ebw[m] = fast_exp2(c2 * s) * comp_w[m] * (1.0f / N_BAG);
    }
    __syncthreads();
    if (tid < N_BAG)
        a2c[tid] = c2t * (a2part[tid][0] + a2part[tid][1] +
                          a2part[tid][2] + a2part[tid][3]);
    __syncthreads();

    // ---- per-wave register state: 8 A-frags + 8 seed rows (64 VGPR) ----
    const int lane = tid & 63, wv = tid >> 6;
    const int r = lane & 15, gq = lane >> 4, rowg = gq * 4;
    short8v Ah[NTILES];
    f32x4   a2f[NTILES];
#pragma unroll
    for (int t = 0; t < NTILES; ++t) {
        Ah[t]  = Af[t][lane];
        a2f[t] = *(const f32x4*)&a2c[t * 16 + rowg];
    }

    const int    m_base = wv * (MT_PW * 16) + r;    // m for tile i = m_base + 16*i
    const float* cxp    = c_x + (size_t)m_base * DXD + 8 * gq;

    float4 p0 = *(const float4*)(cxp);
    float4 p1 = *(const float4*)(cxp + 4);

#pragma unroll
    for (int i = 0; i < MT_PW; ++i) {
        // prefetch next c_x tile (static predicate under full unroll)
        float4 q0, q1;
        if (i + 1 < MT_PW) {
            q0 = *(const float4*)(cxp + (i + 1) * 16 * DXD);
            q1 = *(const float4*)(cxp + (i + 1) * 16 * DXD + 4);
        }
        union { unsigned int u4[4]; short8v s8; } bc;
        bc.u4[0] = pkbf(p0.x, p0.y); bc.u4[1] = pkbf(p0.z, p0.w);
        bc.u4[2] = pkbf(p1.x, p1.y); bc.u4[3] = pkbf(p1.z, p1.w);

        float cs_t = 0.f, cs0 = 0.f, cs1 = 0.f, cs2 = 0.f;
#pragma unroll
        for (int t = 0; t < NTILES; ++t) {
            f32x4 acc = __builtin_amdgcn_mfma_f32_16x16x32_bf16(Ah[t], bc.s8, a2f[t], 0, 0, 0);
            cs_t += fast_exp2(acc[0] * 0.015625f);     // trans pipe (t/64)
            cs0 = exp2lut_acc(acc[1], lut, cs0);       // VALU + DS pipes
            cs1 = exp2lut_acc(acc[2], lut, cs1);
            cs2 = exp2lut_acc(acc[3], lut, cs2);
        }
        float csum = (cs_t + cs0) + (cs1 + cs2);
        csum += __shfl_xor(csum, 16, 64);
        csum += __shfl_xor(csum, 32, 64);           // sum over all 128 n
        if (lane < 16) ow_s[m_base + 16 * i] = csum;
        p0 = q0; p1 = q1;
    }
    __syncthreads();

    // ---- phase 2: coalesced projection over all 2048 m's; block-reduce; write out ----
    float vals[DYD + 1];
#pragma unroll
    for (int v = 0; v <= DYD; ++v) vals[v] = 0.f;
#pragma unroll
    for (int k = 0; k < 2; ++k) {
        const int m = tid + 1024 * k;
        const float w = ow_s[m] * ebw[m];
        const float2* cyp = (const float2*)(c_y + (size_t)m * DYD);
        float2 y0 = cyp[0], y1 = cyp[1], y2 = cyp[2], y3 = cyp[3], y4 = cyp[4];
        float cy[DYD] = {y0.x, y0.y, y1.x, y1.y, y2.x, y2.y, y3.x, y3.y, y4.x, y4.y};
        float ny = 0.f;
#pragma unroll
        for (int d = 0; d < DYD; ++d) ny = fmaf(cy[d], cy[d], ny);
        const float yw = w * __builtin_amdgcn_rcpf(ny);
        vals[0] += w;
#pragma unroll
        for (int d = 0; d < DYD; ++d) vals[1 + d] = fmaf(yw, cy[d] * cy[d], vals[1 + d]);
    }
#pragma unroll
    for (int v = 0; v <= DYD; ++v) {
        float x = vals[v];
#pragma unroll
        for (int off = 32; off > 0; off >>= 1) x += __shfl_down(x, off, 64);
        if (lane == 0) red[wv][v] = x;
    }
    __syncthreads();
    if (tid <= DYD) {
        float s = 0.f;
#pragma unroll
        for (int w16 = 0; w16 < WAVES; ++w16) s += red[w16][tid];
        sm[tid] = s;
    }
    __syncthreads();
    if (tid < DYD) {
        float d = sm[0];
        d = (d == 0.f) ? 1e-16f : d;
        out[(size_t)b * DYD + tid] = sm[1 + tid] / d;
    }
}

extern "C" void kernel_launch(void* const* d_in, const int* in_sizes, int n_in,
                              void* d_out, int out_size, void* d_ws, size_t ws_size,
                              hipStream_t stream) {
    const float* X      = (const float*)d_in[0];  // (256,128,32)
    const float* sigma  = (const float*)d_in[1];  // scalar
    const float* c_x    = (const float*)d_in[2];  // (2048,32)
    const float* c_y    = (const float*)d_in[3];  // (2048,10)
    const float* comp_w = (const float*)d_in[4];  // (2048,)
    float*       out    = (float*)d_out;          // (256,10)

    fused_kernel<<<BS, 1024, 0, stream>>>(X, sigma, c_x, c_y, comp_w, out);
}

// Round 12
// 27.862 us; speedup vs baseline: 1.3172x; 1.2195x over previous
//
#include <hip/hip_runtime.h>
#include <hip/hip_bf16.h>

// Problem dims (fixed by setup_inputs)
#define BS     256
#define N_BAG  128
#define DXD    32
#define DYD    10
#define M_COMP 2048
#define NTILES 8              // n-tiles (128/16)
#define WAVES  16             // block = 1024 threads
#define MT_PW  8              // m-tiles per wave (128 tiles / 16 waves)

typedef __attribute__((ext_vector_type(8))) short short8v;   // 8 bf16 (4 VGPRs)
typedef __attribute__((ext_vector_type(4))) float f32x4;

static __device__ __forceinline__ unsigned int pkbf(float a, float b) {
    // RNE pack of two f32 -> 2x bf16 in one u32 (v_cvt_pk_bf16_f32)
    unsigned short ha = __bfloat16_as_ushort(__float2bfloat16(a));
    unsigned short hb = __bfloat16_as_ushort(__float2bfloat16(b));
    return (unsigned int)ha | ((unsigned int)hb << 16);
}
static __device__ __forceinline__ float fast_exp2(float x) {
#if __has_builtin(__builtin_amdgcn_exp2f)
    return __builtin_amdgcn_exp2f(x);     // trans pipe
#else
    return __expf(x * 0.6931471805599453f);
#endif
}

// One block per batch row b; 16 waves; 1 block/CU (4 waves/SIMD, <=128 VGPR).
// K^2 = 2^(c2*a2[n] - 2c2*dot) * 2^(c2*b2[m]); MFMA emits the exponent directly.
// HOT-LOOP TAIL REMOVED: no cross-lane shuffles, no exec-masked stores — every lane
// writes its quarter-partial to ow4[gq][m]; phase 2 sums the 4 quarters.
// 2-tile interleave doubles independent MFMA->exp streams per wave.
__global__ __launch_bounds__(1024, 4) void fused_kernel(
    const float* __restrict__ X,        // (BS, N_BAG, DXD)
    const float* __restrict__ sig_p,    // scalar
    const float* __restrict__ c_x,      // (M_COMP, DXD)
    const float* __restrict__ c_y,      // (M_COMP, DYD)
    const float* __restrict__ comp_w,   // (M_COMP,)
    float* __restrict__ out)            // (BS, DYD)
{
    __shared__ short8v Af[NTILES][64];     // A' fragments (8 KB)
    __shared__ float   a2part[N_BAG][4];
    __shared__ float   a2c[N_BAG];         // c2 * ||x_n||^2
    __shared__ float   ebw[M_COMP];        // 2^(c2*b2[m]) * comp_w[m] / N  (8 KB)
    __shared__ float   ow4[4][M_COMP];     // quarter partial sums per m (32 KB)
    __shared__ float   red[WAVES][12];
    __shared__ float   sm[12];

    const int tid = threadIdx.x;
    const int b   = blockIdx.x;

    const float sgm = fmaxf(sig_p[0], 1e-3f);
    const float c2  = -1.4426950408889634f / (sgm * sgm);  // -log2(e)/sigma^2 (<0)
    const float sA  = -2.0f * c2;                          // A-side scale (>0)

    // ---- stage A' = sA*X as bf16 fragments + row norms (threads 0..511) ----
    if (tid < 512) {
        const int n = tid >> 2, g4 = tid & 3;
        const float4* Xr = (const float4*)(X + ((size_t)(b * N_BAG + n) * DXD + 8 * g4));
        float4 v0 = Xr[0], v1 = Xr[1];
        float s = 0.f;
        s = fmaf(v0.x, v0.x, s); s = fmaf(v0.y, v0.y, s);
        s = fmaf(v0.z, v0.z, s); s = fmaf(v0.w, v0.w, s);
        s = fmaf(v1.x, v1.x, s); s = fmaf(v1.y, v1.y, s);
        s = fmaf(v1.z, v1.z, s); s = fmaf(v1.w, v1.w, s);
        union { unsigned int u4[4]; short8v s8; } cv;
        cv.u4[0] = pkbf(sA * v0.x, sA * v0.y); cv.u4[1] = pkbf(sA * v0.z, sA * v0.w);
        cv.u4[2] = pkbf(sA * v1.x, sA * v1.y); cv.u4[3] = pkbf(sA * v1.z, sA * v1.w);
        Af[n >> 4][g4 * 16 + (n & 15)] = cv.s8;
        a2part[n][g4] = s;
    }
    // ---- stage ebw[m] = 2^(c2*||c_x[m]||^2) * comp_w[m]/N for all 2048 m ----
#pragma unroll
    for (int k = 0; k < 2; ++k) {
        const int m = tid + 1024 * k;
        const float4* cp = (const float4*)(c_x + (size_t)m * DXD);
        float s = 0.f;
#pragma unroll
        for (int j = 0; j < 8; ++j) {
            float4 v = cp[j];
            s = fmaf(v.x, v.x, s); s = fmaf(v.y, v.y, s);
            s = fmaf(v.z, v.z, s); s = fmaf(v.w, v.w, s);
        }
        ebw[m] = fast_exp2(c2 * s) * comp_w[m] * (1.0f / N_BAG);
    }
    __syncthreads();
    if (tid < N_BAG)
        a2c[tid] = c2 * (a2part[tid][0] + a2part[tid][1] +
                         a2part[tid][2] + a2part[tid][3]);
    __syncthreads();

    // ---- per-wave register state: 8 A-frags + 8 seed rows (64 VGPR) ----
    const int lane = tid & 63, wv = tid >> 6;
    const int r = lane & 15, gq = lane >> 4, rowg = gq * 4;
    short8v Ah[NTILES];
    f32x4   a2f[NTILES];
#pragma unroll
    for (int t = 0; t < NTILES; ++t) {
        Ah[t]  = Af[t][lane];
        a2f[t] = *(const f32x4*)&a2c[t * 16 + rowg];
    }

    const int    m_base = wv * (MT_PW * 16) + r;    // m for tile i = m_base + 16*i
    const float* cxp    = c_x + (size_t)m_base * DXD + 8 * gq;

    // software pipeline: loads for pair ip preloaded during pair ip-1
    float4 pA0 = *(const float4*)(cxp);
    float4 pA1 = *(const float4*)(cxp + 4);
    float4 pB0 = *(const float4*)(cxp + 512);
    float4 pB1 = *(const float4*)(cxp + 516);

#pragma unroll
    for (int ip = 0; ip < 4; ++ip) {                // 4 pairs of m-tiles
        float4 qA0, qA1, qB0, qB1;
        if (ip + 1 < 4) {
            const float* nx = cxp + (ip + 1) * 1024;
            qA0 = *(const float4*)(nx);
            qA1 = *(const float4*)(nx + 4);
            qB0 = *(const float4*)(nx + 512);
            qB1 = *(const float4*)(nx + 516);
        }
        union { unsigned int u4[4]; short8v s8; } bca, bcb;
        bca.u4[0] = pkbf(pA0.x, pA0.y); bca.u4[1] = pkbf(pA0.z, pA0.w);
        bca.u4[2] = pkbf(pA1.x, pA1.y); bca.u4[3] = pkbf(pA1.z, pA1.w);
        bcb.u4[0] = pkbf(pB0.x, pB0.y); bcb.u4[1] = pkbf(pB0.z, pB0.w);
        bcb.u4[2] = pkbf(pB1.x, pB1.y); bcb.u4[3] = pkbf(pB1.z, pB1.w);

        float a0 = 0.f, a1 = 0.f, a2s = 0.f, a3 = 0.f;   // chains, tile A
        float b0 = 0.f, b1 = 0.f, b2s = 0.f, b3 = 0.f;   // chains, tile B
#pragma unroll
        for (int t = 0; t < NTILES; ++t) {
            f32x4 accA = __builtin_amdgcn_mfma_f32_16x16x32_bf16(Ah[t], bca.s8, a2f[t], 0, 0, 0);
            f32x4 accB = __builtin_amdgcn_mfma_f32_16x16x32_bf16(Ah[t], bcb.s8, a2f[t], 0, 0, 0);
            a0 += fast_exp2(accA[0]); a1 += fast_exp2(accA[1]);
            a2s += fast_exp2(accA[2]); a3 += fast_exp2(accA[3]);
            b0 += fast_exp2(accB[0]); b1 += fast_exp2(accB[1]);
            b2s += fast_exp2(accB[2]); b3 += fast_exp2(accB[3]);
        }
        // per-lane quarter-partial (sum over this lane-group's 32 n-rows); no shuffles
        ow4[gq][m_base + 32 * ip]      = (a0 + a1) + (a2s + a3);
        ow4[gq][m_base + 32 * ip + 16] = (b0 + b1) + (b2s + b3);
        pA0 = qA0; pA1 = qA1; pB0 = qB0; pB1 = qB1;
    }
    __syncthreads();

    // ---- phase 2: coalesced projection over all 2048 m's; block-reduce; write out ----
    float vals[DYD + 1];
#pragma unroll
    for (int v = 0; v <= DYD; ++v) vals[v] = 0.f;
#pragma unroll
    for (int k = 0; k < 2; ++k) {
        const int m = tid + 1024 * k;
        const float w = ((ow4[0][m] + ow4[1][m]) + (ow4[2][m] + ow4[3][m])) * ebw[m];
        const float2* cyp = (const float2*)(c_y + (size_t)m * DYD);
        float2 y0 = cyp[0], y1 = cyp[1], y2 = cyp[2], y3 = cyp[3], y4 = cyp[4];
        float cy[DYD] = {y0.x, y0.y, y1.x, y1.y, y2.x, y2.y, y3.x, y3.y, y4.x, y4.y};
        float ny = 0.f;
#pragma unroll
        for (int d = 0; d < DYD; ++d) ny = fmaf(cy[d], cy[d], ny);
        const float yw = w * __builtin_amdgcn_rcpf(ny);
        vals[0] += w;
#pragma unroll
        for (int d = 0; d < DYD; ++d) vals[1 + d] = fmaf(yw, cy[d] * cy[d], vals[1 + d]);
    }
#pragma unroll
    for (int v = 0; v <= DYD; ++v) {
        float x = vals[v];
#pragma unroll
        for (int off = 32; off > 0; off >>= 1) x += __shfl_down(x, off, 64);
        if (lane == 0) red[wv][v] = x;
    }
    __syncthreads();
    if (tid <= DYD) {
        float s = 0.f;
#pragma unroll
        for (int w16 = 0; w16 < WAVES; ++w16) s += red[w16][tid];
        sm[tid] = s;
    }
    __syncthreads();
    if (tid < DYD) {
        float d = sm[0];
        d = (d == 0.f) ? 1e-16f : d;
        out[(size_t)b * DYD + tid] = sm[1 + tid] / d;
    }
}

extern "C" void kernel_launch(void* const* d_in, const int* in_sizes, int n_in,
                              void* d_out, int out_size, void* d_ws, size_t ws_size,
                              hipStream_t stream) {
    const float* X      = (const float*)d_in[0];  // (256,128,32)
    const float* sigma  = (const float*)d_in[1];  // scalar
    const float* c_x    = (const float*)d_in[2];  // (2048,32)
    const float* c_y    = (const float*)d_in[3];  // (2048,10)
    const float* comp_w = (const float*)d_in[4];  // (2048,)
    float*       out    = (float*)d_out;          // (256,10)

    fused_kernel<<<BS, 1024, 0, stream>>>(X, sigma, c_x, c_y, comp_w, out);
}